// Round 4
// baseline (299.613 us; speedup 1.0000x reference)
//
#include <hip/hip_runtime.h>
#include <math.h>

// TimeNormalization: EMA over time (alpha=0.1) of x and x^2, then normalize.
// x: [B=32, T=8192, F=128] fp32; state: [2,B,F] fp32 (s_{-1}).
// Outputs (concat in d_out): x_norm [B,T,F] fp32, final_state [2,B,F] fp32.
//
// Chunked-parallel with warmup: 0.9^128 ~ 1.4e-6, so each chunk of L steps
// warms up over the previous W=128 steps. Chunks whose warmup would start
// at/before t=0 instead start from the exact initial state at t=0 (exact
// chain, no approximation).
//
// R8: minimal diff from the known-good R0 kernel (which measured 97 us,
// 2.75 TB/s, Occupancy 10%). R5-R7 (explicit 8-deep prefetch buffer family)
// failed the container twice each, three rounds running, with no counters —
// bisecting: this round keeps R0's exact code shape (compiler-scheduled
// unroll-8 loops, no prefetch array) and changes ONLY the chunk length
// L 128 -> 64. That doubles the grid (256 -> 512 blocks -> 2 blocks/CU ->
// 8 waves/CU), doubling wave-level memory concurrency, which R0's counters
// identified as the bottleneck (latency-bound at ~4.5 B/cy/CU in flight).
// Warmup re-reads (now 2x per output element) stay L2/L3-absorbed:
// R0's FETCH_SIZE was ~130 MB = ~1x input with 1x amplification already.

constexpr int B = 32, T = 8192, F = 128;
constexpr int L = 64;           // chunk length (R8: halved for 2x occupancy)
constexpr int W = 128;          // warmup window (0.9^128 ~ 1.4e-6)
constexpr int NCHUNK = T / L;   // 128
constexpr int F4 = F / 4;       // 32 float4 lanes per row
constexpr int WPB = 8;          // workers per 256-thread block
constexpr float ALPHA = 0.1f;
constexpr float CDECAY = 0.9f;  // 1 - ALPHA
constexpr float EPS = 1e-3f;

typedef float v4f __attribute__((ext_vector_type(4)));

__global__ __launch_bounds__(256) void TimeNormalization_kernel(
    const float* __restrict__ x,
    const float* __restrict__ state,
    float* __restrict__ out) {
    const int j = threadIdx.x & 31;                       // v4f lane in row
    const int w = blockIdx.x * WPB + (threadIdx.x >> 5);  // worker id
    const int b = w >> 7;                  // w / NCHUNK (NCHUNK=128)
    const int chunk = w & (NCHUNK - 1);    // w % NCHUNK
    const int t0 = chunk * L;

    const v4f* __restrict__ x4 = (const v4f*)x;
    const v4f* __restrict__ s4 = (const v4f*)state;
    v4f* __restrict__ o4 = (v4f*)out;

    v4f sm, ss;
    int t = t0 - W;
    if (t <= 0) {
        // Chunks 0 and 1: start from the exact initial state at t=0.
        t = 0;
        sm = s4[b * F4 + j];
        ss = s4[B * F4 + b * F4 + j];
    } else {
        sm = (v4f)0.f;
        ss = (v4f)0.f;
    }

    const v4f* __restrict__ px = x4 + (size_t)b * T * F4 + j;
    v4f* __restrict__ po = o4 + (size_t)b * T * F4 + j;

    // Warmup: build state, no output. Independent 16B loads -> deep pipeline.
    #pragma unroll 8
    for (; t < t0; ++t) {
        v4f v = px[(size_t)t * F4];
        sm = CDECAY * sm + ALPHA * v;        // vector fma
        ss = CDECAY * ss + ALPHA * (v * v);
    }

    // Main: update state, normalize, nontemporal 16B store (streaming output
    // must not evict x from L2/L3 -- warmup reads rely on cache hits).
    #pragma unroll 8
    for (int i = 0; i < L; ++i) {
        const int tt = t0 + i;
        v4f v = px[(size_t)tt * F4];
        sm = CDECAY * sm + ALPHA * v;
        ss = CDECAY * ss + ALPHA * (v * v);
        v4f d = v - sm;
        v4f o;
        o.x = d.x * rsqrtf(ss.x - sm.x * sm.x + EPS);
        o.y = d.y * rsqrtf(ss.y - sm.y * sm.y + EPS);
        o.z = d.z * rsqrtf(ss.z - sm.z * sm.z + EPS);
        o.w = d.w * rsqrtf(ss.w - sm.w * sm.w + EPS);
        __builtin_nontemporal_store(o, &po[(size_t)tt * F4]);
    }

    // Last chunk owns the final-state output.
    if (chunk == NCHUNK - 1) {
        v4f* fs = (v4f*)(out + (size_t)B * T * F);
        fs[b * F4 + j] = sm;                 // mean state
        fs[B * F4 + b * F4 + j] = ss;        // second-moment state
    }
}

extern "C" void kernel_launch(void* const* d_in, const int* in_sizes, int n_in,
                              void* d_out, int out_size, void* d_ws, size_t ws_size,
                              hipStream_t stream) {
    const float* x = (const float*)d_in[0];
    const float* state = (const float*)d_in[1];
    float* out = (float*)d_out;

    dim3 grid((B * NCHUNK) / WPB);   // 512 blocks -> 2 blocks/CU
    dim3 block(256);                 // 8 workers of 32 lanes each
    TimeNormalization_kernel<<<grid, block, 0, stream>>>(x, state, out);
}

// Round 5
// 266.053 us; speedup vs baseline: 1.1261x; 1.1261x over previous
//
#include <hip/hip_runtime.h>
#include <math.h>

// TimeNormalization: EMA over time (alpha=0.1) of x and x^2, then normalize.
// x: [B=32, T=8192, F=128] fp32; state: [2,B,F] fp32 (s_{-1}).
// Outputs (concat in d_out): x_norm [B,T,F] fp32, final_state [2,B,F] fp32.
//
// Chunked-parallel with warmup: 0.9^128 ~ 1.4e-6, so each chunk warms up over
// the previous W=128 steps from zero state (chunks whose warmup would start
// at/before t=0 instead start from the exact initial state -> exact chain).
//
// R9 evidence chain:
//  - R0 (L=128, 1 blk/CU): 97us, 2.75 TB/s, VGPR=52 (compiler kept ~8 loads
//    in flight), Occupancy 10%. Latency/concurrency-bound, not BW-bound.
//  - R8 (L=64, 2 blk/CU, same code shape): 142us, VGPR=20 — the compiler
//    DROPPED the 8-deep load batching when L changed; per-wave in-flight fell
//    4x, net in-flight bytes fell despite 2x waves. Lesson: per-wave ILP is
//    the dominant lever and must be forced, not left to unroll heuristics.
//  - R9 (this): explicit rotating v4f buf[8] pipeline => 8KB/wave in flight
//    through steady state, guaranteed; L=64 => 512 blocks, 8 waves/CU =>
//    64KB/CU in flight >> ~21KB needed for 6 TB/s @ 900cy HBM latency.
//    (R5-R7 container failures re-audited: no OOB; attributed to infra.)

constexpr int B = 32, T = 8192, F = 128;
constexpr int L = 64;           // chunk length (2 blocks/CU, 8 waves/CU)
constexpr int W = 128;          // warmup window (0.9^128 ~ 1.4e-6)
constexpr int NCHUNK = T / L;   // 128
constexpr int F4 = F / 4;       // 32 float4 lanes per row
constexpr int WPB = 8;          // workers per 256-thread block
constexpr int PF = 8;           // software-pipeline depth (loads in flight)
constexpr float ALPHA = 0.1f;
constexpr float CDECAY = 0.9f;  // 1 - ALPHA
constexpr float EPS = 1e-3f;

typedef float v4f __attribute__((ext_vector_type(4)));

__global__ __launch_bounds__(256) void TimeNormalization_kernel(
    const float* __restrict__ x,
    const float* __restrict__ state,
    float* __restrict__ out) {
    const int j = threadIdx.x & 31;                       // v4f lane in row
    const int w = blockIdx.x * WPB + (threadIdx.x >> 5);  // worker id
    const int b = w >> 7;                  // w / NCHUNK (NCHUNK=128)
    const int chunk = w & (NCHUNK - 1);    // w % NCHUNK
    const int t0 = chunk * L;

    const v4f* __restrict__ x4 = (const v4f*)x;
    const v4f* __restrict__ s4 = (const v4f*)state;
    v4f* __restrict__ o4 = (v4f*)out;

    const v4f* __restrict__ px = x4 + (size_t)b * T * F4 + j;
    v4f* __restrict__ po = o4 + (size_t)b * T * F4 + j;

    v4f sm, ss;
    int t = t0 - W;
    if (t <= 0) {
        // Warmup (if any) runs from t=0 with the exact initial state: the
        // resulting chain is exact, not an approximation.
        t = 0;
        sm = s4[b * F4 + j];
        ss = s4[B * F4 + b * F4 + j];
    } else {
        sm = (v4f)0.f;
        ss = (v4f)0.f;
    }

    v4f buf[PF];

    // ---- Warmup: build state, no output. 8-deep rotating pipeline. ----
    // nwarm = t0 - t is in {0, 64, 128}: always a multiple of PF.
    if (t < t0) {
        #pragma unroll
        for (int k = 0; k < PF; ++k) buf[k] = px[(size_t)(t + k) * F4];
        t += PF;
        for (; t < t0; t += PF) {          // steady state: consume + refill
            #pragma unroll
            for (int k = 0; k < PF; ++k) {
                v4f v = buf[k];
                buf[k] = px[(size_t)(t + k) * F4];   // keep 8 in flight
                sm = CDECAY * sm + ALPHA * v;
                ss = CDECAY * ss + ALPHA * (v * v);
            }
        }
        #pragma unroll
        for (int k = 0; k < PF; ++k) {               // drain
            v4f v = buf[k];
            sm = CDECAY * sm + ALPHA * v;
            ss = CDECAY * ss + ALPHA * (v * v);
        }
    }

    // ---- Main: update state, normalize, nontemporal 16B store. ----
    // (streaming output must not evict x from L2/L3 -- warmup re-reads of
    // neighbor chunks rely on cache hits; R0 FETCH_SIZE showed ~1x HBM fetch)
    #pragma unroll
    for (int k = 0; k < PF; ++k) buf[k] = px[(size_t)(t0 + k) * F4];
    for (int i = 0; i < L - PF; i += PF) {           // steady state (7 iters)
        #pragma unroll
        for (int k = 0; k < PF; ++k) {
            const int tt = t0 + i + k;
            v4f v = buf[k];
            buf[k] = px[(size_t)(tt + PF) * F4];     // keep 8 in flight
            sm = CDECAY * sm + ALPHA * v;
            ss = CDECAY * ss + ALPHA * (v * v);
            v4f d = v - sm;
            v4f o;
            o.x = d.x * rsqrtf(ss.x - sm.x * sm.x + EPS);
            o.y = d.y * rsqrtf(ss.y - sm.y * sm.y + EPS);
            o.z = d.z * rsqrtf(ss.z - sm.z * sm.z + EPS);
            o.w = d.w * rsqrtf(ss.w - sm.w * sm.w + EPS);
            __builtin_nontemporal_store(o, &po[(size_t)tt * F4]);
        }
    }
    #pragma unroll
    for (int k = 0; k < PF; ++k) {                   // drain last 8 steps
        const int tt = t0 + (L - PF) + k;
        v4f v = buf[k];
        sm = CDECAY * sm + ALPHA * v;
        ss = CDECAY * ss + ALPHA * (v * v);
        v4f d = v - sm;
        v4f o;
        o.x = d.x * rsqrtf(ss.x - sm.x * sm.x + EPS);
        o.y = d.y * rsqrtf(ss.y - sm.y * sm.y + EPS);
        o.z = d.z * rsqrtf(ss.z - sm.z * sm.z + EPS);
        o.w = d.w * rsqrtf(ss.w - sm.w * sm.w + EPS);
        __builtin_nontemporal_store(o, &po[(size_t)tt * F4]);
    }

    // Last chunk owns the final-state output.
    if (chunk == NCHUNK - 1) {
        v4f* fs = (v4f*)(out + (size_t)B * T * F);
        fs[b * F4 + j] = sm;                 // mean state
        fs[B * F4 + b * F4 + j] = ss;        // second-moment state
    }
}

extern "C" void kernel_launch(void* const* d_in, const int* in_sizes, int n_in,
                              void* d_out, int out_size, void* d_ws, size_t ws_size,
                              hipStream_t stream) {
    const float* x = (const float*)d_in[0];
    const float* state = (const float*)d_in[1];
    float* out = (float*)d_out;

    dim3 grid((B * NCHUNK) / WPB);   // 512 blocks -> 2 blocks/CU
    dim3 block(256);                 // 8 workers of 32 lanes each
    TimeNormalization_kernel<<<grid, block, 0, stream>>>(x, state, out);
}